// Round 9
// baseline (1661.662 us; speedup 1.0000x reference)
//
#include <hip/hip_runtime.h>

// NeuralODE SSP-RK3, z:[32,16,8192] fp32, W:[16,16,5], 100 steps, h=t/100.
// R5 structure + layout (empirical best: transposed fp32 state [b][x][ch],
// dispatch boundary = grid barrier), with SPK raised 5 -> 10 to halve the
// number of dispatch boundaries (each boundary costs ~38us of state
// re-streaming + launch overhead; L2 is written back at kernel end).
// Per dispatch: 10 RK steps = 30 stages via LDS halo recompute. Slab =
// 256 interior + 64 halo cols/side = 384 cols (24 tiles); validity shrinks
// 2 cols/stage, 60 <= 64. fp32 state in registers across the 10 steps; conv
// inputs/weights bf16 in LDS; conv = 3x mfma_f32_16x16x32_bf16 per 16-col
// tile (K-chunk = tap-pair x 16 in-ch). BC (x<10 <- x=10; x>8181 <- x=8181)
// via in-wave shuffles every stage (also quarantines domain-edge halo junk:
// 2 cols/stage drift vs 10-wide zone reset every stage).
// R8 lesson: lane-packed global layout REGRESSED (76 vs 56 us/dispatch);
// wave stores here already cover full 64B lines. Keep [x][ch].

#define NCH    16
#define LL     8192
#define TX     256
#define HALOC  64
#define SLABC  384          // 24 tiles of 16 cols; global x = x0 - 64 + s
#define NBX    32
#define NB     32
#define NSTEPS 100
#define SPK    10           // steps fused per kernel
#define NKER   (NSTEPS / SPK)
#define NTI    6            // tiles per thread = 24 tiles / 4 waves

typedef __bf16 bf16x8 __attribute__((ext_vector_type(8)));
typedef __bf16 bf16x4 __attribute__((ext_vector_type(4)));
typedef float  f32x4  __attribute__((ext_vector_type(4)));

// LDS: S[col][ch] bf16; XOR-swizzle 8-ch half on col bit2 (col stride = 8
// banks -> pairs of cols 2-way alias, free on CDNA4).
__device__ __forceinline__ int ldsIdx(int col, int ch) {
  return col * NCH + (ch ^ ((col & 4) << 1));
}

__global__ __launch_bounds__(256) void transpose_kernel(const float* __restrict__ in,
                                                        float* __restrict__ out) {
  const int b = blockIdx.y;
  const int x = blockIdx.x * 256 + threadIdx.x;
  const float* __restrict__ ib = in + (size_t)b * NCH * LL;
  float* __restrict__ ob = out + (size_t)b * NCH * LL;
  float v[NCH];
#pragma unroll
  for (int c = 0; c < NCH; ++c) v[c] = ib[c * LL + x];
#pragma unroll
  for (int c = 0; c < NCH; c += 4)
    *(float4*)(ob + (size_t)x * NCH + c) = make_float4(v[c], v[c+1], v[c+2], v[c+3]);
}

__global__ __launch_bounds__(256, 4) void multistep_kernel(
    const float* __restrict__ zin,   // fp32 transposed [b][x][ch]
    float* __restrict__ zout,        // fp32 transposed (row-major if finalKer)
    const float* __restrict__ W,     // [o][i][k] 16x16x5
    const int* __restrict__ tptr, int finalKer)
{
  __shared__ __align__(16) __bf16 S[2][SLABC * NCH];

  const int b = blockIdx.y, bx = blockIdx.x;
  const int x0 = bx * TX;
  const bool leftE = (bx == 0), rightE = (bx == NBX - 1);
  const float h = (float)(*tptr) / (float)NSTEPS;
  const int tid = threadIdx.x, lane = tid & 63, wv = tid >> 6;
  const int g = lane >> 4, n = lane & 15;

  const float* __restrict__ zb = zin + (size_t)b * NCH * LL;
  float* __restrict__ ob = zout + (size_t)b * NCH * LL;

  // A fragments (weights, bf16). K-chunk c: taps kk = 2c + (g>>1);
  // lane elems: in-ch i = (g&1)*8 + j; out-ch = n. kk==5 lanes get 0.
  bf16x8 afrag[3];
#pragma unroll
  for (int c = 0; c < 3; ++c) {
    const int kk = c * 2 + (g >> 1);
#pragma unroll
    for (int j = 0; j < 8; ++j) {
      const int i = (g & 1) * 8 + j;
      const float wval = (kk < 5) ? W[n * (NCH * 5) + i * 5 + kk] : 0.0f;
      afrag[c][j] = (__bf16)wval;
    }
  }

  // Load z slab -> S[0] (bf16, swizzled). 64B-line coalesced per quarter-wave.
  for (int q = tid; q < SLABC * 4; q += 256) {
    const int s = q >> 2, cg = (q & 3) * 4;
    int gx = x0 - HALOC + s;
    gx = min(max(gx, 0), LL - 1);
    const float4 v = *(const float4*)(zb + (size_t)gx * NCH + cg);
    bf16x4 bv = { (__bf16)v.x, (__bf16)v.y, (__bf16)v.z, (__bf16)v.w };
    *(bf16x4*)(&S[0][ldsIdx(s, cg)]) = bv;
  }

  // fp32 state in registers: thread owns (x = 16t+n, ch g*4..+3), t = wv+4ti.
  // These 16B loads hit lines the slab loop just fetched (L1/L2 resident).
  f32x4 kz[NTI], kf[NTI];
#pragma unroll
  for (int ti = 0; ti < NTI; ++ti) {
    const int t = wv + 4 * ti;
    int gx = x0 - HALOC + 16 * t + n;
    gx = min(max(gx, 0), LL - 1);
    kz[ti] = *(const f32x4*)(zb + (size_t)gx * NCH + g * 4);
    kf[ti] = (f32x4){0.f, 0.f, 0.f, 0.f};
  }
  __syncthreads();

  // One RK stage: v = az*z + ak*kf + agh*conv(RS); BC shuffles; kf<-v;
  // mode 0: bf16 -> LDS; 1: fp32 -> global transposed; 2: final row-major.
  auto stage = [&](float az, float ak, float agh, int rb, bool updZ, int mode) {
    const __bf16* RS = S[rb];
    __bf16* WS = S[rb ^ 1];
#pragma unroll
    for (int ti = 0; ti < NTI; ++ti) {
      const int t = wv + 4 * ti;
      f32x4 acc = {0.f, 0.f, 0.f, 0.f};
#pragma unroll
      for (int c = 0; c < 3; ++c) {
        const int kk = c * 2 + (g >> 1);
        int s = 16 * t + n + kk - 2;       // read col = write col + (kk-2)
        s = min(max(s, 0), SLABC - 1);     // clamped cols are shrink-invalid halo
        bf16x8 bfrag = *(const bf16x8*)(&RS[ldsIdx(s, (g & 1) * 8)]);
        acc = __builtin_amdgcn_mfma_f32_16x16x32_bf16(afrag[c], bfrag, acc, 0, 0, 0);
      }
      f32x4 v;
#pragma unroll
      for (int r = 0; r < 4; ++r)
        v[r] = az * kz[ti][r] + ak * kf[ti][r] + agh * acc[r];

      // BC: x 0..9 <- x=10 (t=4 lane n=10); x 8182..8191 <- x=8181 (t=19 n=5)
      if (leftE && t == 4) {
#pragma unroll
        for (int r = 0; r < 4; ++r) {
          float sv = __shfl(v[r], (lane & 48) | 10, 64);
          if (n < 10) v[r] = sv;
        }
      }
      if (rightE && t == 19) {
#pragma unroll
        for (int r = 0; r < 4; ++r) {
          float sv = __shfl(v[r], (lane & 48) | 5, 64);
          if (n > 5) v[r] = sv;
        }
      }

      kf[ti] = v;
      if (updZ) kz[ti] = v;

      if (mode == 0) {
        bf16x4 bv = { (__bf16)v[0], (__bf16)v[1], (__bf16)v[2], (__bf16)v[3] };
        *(bf16x4*)(&WS[ldsIdx(16 * t + n, g * 4)]) = bv;
      } else if (t >= 4 && t <= 19) {      // interior tiles: gx in [x0, x0+256)
        const int xg = x0 - HALOC + 16 * t + n;
        if (mode == 1) {
          *(f32x4*)(ob + (size_t)xg * NCH + g * 4) = v;   // wave covers full lines
        } else {
#pragma unroll
          for (int r = 0; r < 4; ++r) ob[(size_t)(g * 4 + r) * LL + xg] = v[r];
        }
      }
    }
  };

  const float c13 = 1.0f / 3.0f, c23 = 2.0f / 3.0f;
  int rb = 0;
#pragma unroll 1
  for (int sp = 0; sp < SPK; ++sp) {
    const bool lastStep = (sp == SPK - 1);
    stage(1.0f, 0.0f, h, rb, false, 0);
    __syncthreads(); rb ^= 1;
    stage(0.75f, 0.25f, 0.25f * h, rb, false, 0);
    __syncthreads(); rb ^= 1;
    if (!lastStep) {
      stage(c13, c23, c23 * h, rb, true, 0);
      __syncthreads(); rb ^= 1;
    } else {
      stage(c13, c23, c23 * h, rb, true, finalKer ? 2 : 1);
    }
  }
}

extern "C" void kernel_launch(void* const* d_in, const int* in_sizes, int n_in,
                              void* d_out, int out_size, void* d_ws, size_t ws_size,
                              hipStream_t stream) {
  const float* z0 = (const float*)d_in[0];
  const float* W  = (const float*)d_in[1];
  const int*   t  = (const int*)d_in[2];

  float* Q = (float*)d_out;   // transposed intermediate; final row-major dest
  float* P = (float*)d_ws;    // 16 MiB scratch

  dim3 grid(NBX, NB), block(256);
  transpose_kernel<<<grid, block, 0, stream>>>(z0, Q);

  // 10 dispatches; even count ends in Q = d_out.
  for (int k = 1; k <= NKER; ++k) {
    if (k & 1) multistep_kernel<<<grid, block, 0, stream>>>(Q, P, W, t, 0);
    else       multistep_kernel<<<grid, block, 0, stream>>>(P, Q, W, t, k == NKER);
  }
}

// Round 10
// 924.324 us; speedup vs baseline: 1.7977x; 1.7977x over previous
//
#include <hip/hip_runtime.h>

// NeuralODE SSP-RK3, z:[32,16,8192] fp32, W:[16,16,5], 100 steps, h=t/100.
// R5 structure: 20 dispatches x 5 fused RK steps (15 stages) via LDS halo
// recompute; transposed fp32 state [b][x][ch]; conv = 3x
// mfma_f32_16x16x32_bf16 per 16-col tile (K-chunk = tap-pair x 16 in-ch);
// conv inputs/weights bf16, state/pointwise fp32; BC via in-wave shuffles.
// R9 LESSON: per-thread state ARRAYS inside a lambda were kept in scratch
// (VGPR_Count=64, phantom HBM traffic: +60MB write @NTI=5, +270MB fetch
// @NTI=6, dur tracking hbm_bytes/2.7TB/s). THIS ROUND: no lambdas, no local
// arrays — named f32x4 kz0..4/kf0..4, af0..2, template<MODE,UPDZ> inline
// stage fn taking f32x4& — forcing full register promotion.

#define NCH    16
#define LL     8192
#define TX     256
#define HALOC  32
#define SLABC  320          // 20 tiles of 16 cols; global x = x0 - 32 + s
#define NBX    32
#define NB     32
#define NSTEPS 100
#define SPK    5
#define NKER   (NSTEPS / SPK)

typedef __bf16 bf16x8 __attribute__((ext_vector_type(8)));
typedef __bf16 bf16x4 __attribute__((ext_vector_type(4)));
typedef float  f32x4  __attribute__((ext_vector_type(4)));

__device__ __forceinline__ int ldsIdx(int col, int ch) {
  return col * NCH + (ch ^ ((col & 4) << 1));
}

__global__ __launch_bounds__(256) void transpose_kernel(const float* __restrict__ in,
                                                        float* __restrict__ out) {
  const int b = blockIdx.y;
  const int x = blockIdx.x * 256 + threadIdx.x;
  const float* __restrict__ ib = in + (size_t)b * NCH * LL;
  float* __restrict__ ob = out + (size_t)b * NCH * LL;
  float v[NCH];
#pragma unroll
  for (int c = 0; c < NCH; ++c) v[c] = ib[c * LL + x];
#pragma unroll
  for (int c = 0; c < NCH; c += 4)
    *(float4*)(ob + (size_t)x * NCH + c) = make_float4(v[c], v[c+1], v[c+2], v[c+3]);
}

__device__ __forceinline__ bf16x8 mkA(const float* __restrict__ W, int c, int g, int n) {
  const int kk = c * 2 + (g >> 1);
  bf16x8 a;
#pragma unroll
  for (int j = 0; j < 8; ++j) {
    const int i = (g & 1) * 8 + j;
    a[j] = (__bf16)((kk < 5) ? W[n * (NCH * 5) + i * 5 + kk] : 0.0f);
  }
  return a;
}

__device__ __forceinline__ f32x4 ldState(const float* __restrict__ zb, int x0,
                                         int t, int n, int g) {
  int gx = x0 - HALOC + 16 * t + n;
  gx = min(max(gx, 0), LL - 1);
  return *(const f32x4*)(zb + (size_t)gx * NCH + g * 4);
}

// One 16-col tile of one RK stage. MODE 0: bf16 -> WS(LDS). MODE 1: global
// store (transposed fp32, or row-major if finalKer). UPDZ: kz <- v.
template<int MODE, bool UPDZ>
__device__ __forceinline__ void tileStage(
    int t, f32x4& KZ, f32x4& KF, float az, float ak, float agh,
    const __bf16* __restrict__ RS, __bf16* __restrict__ WS,
    bf16x8 af0, bf16x8 af1, bf16x8 af2,
    int lane, int g, int n, bool leftE, bool rightE,
    float* __restrict__ ob, int x0, int finalKer)
{
  f32x4 acc = {0.f, 0.f, 0.f, 0.f};
#pragma unroll
  for (int c = 0; c < 3; ++c) {
    const int kk = c * 2 + (g >> 1);
    int s = 16 * t + n + kk - 2;         // read col = write col + (kk-2)
    s = min(max(s, 0), SLABC - 1);
    const bf16x8 bfrag = *(const bf16x8*)(&RS[ldsIdx(s, (g & 1) * 8)]);
    const bf16x8 a = (c == 0) ? af0 : (c == 1) ? af1 : af2;
    acc = __builtin_amdgcn_mfma_f32_16x16x32_bf16(a, bfrag, acc, 0, 0, 0);
  }
  f32x4 v;
#pragma unroll
  for (int r = 0; r < 4; ++r) v[r] = az * KZ[r] + ak * KF[r] + agh * acc[r];

  // BC: x 0..9 <- x=10 (t=2, lane n=10); x 8182..8191 <- x=8181 (t=17, n=5)
  if (leftE && t == 2) {
#pragma unroll
    for (int r = 0; r < 4; ++r) {
      const float sv = __shfl(v[r], (lane & 48) | 10, 64);
      if (n < 10) v[r] = sv;
    }
  }
  if (rightE && t == 17) {
#pragma unroll
    for (int r = 0; r < 4; ++r) {
      const float sv = __shfl(v[r], (lane & 48) | 5, 64);
      if (n > 5) v[r] = sv;
    }
  }

  KF = v;
  if (UPDZ) KZ = v;

  if (MODE == 0) {
    bf16x4 bv = { (__bf16)v[0], (__bf16)v[1], (__bf16)v[2], (__bf16)v[3] };
    *(bf16x4*)(&WS[ldsIdx(16 * t + n, g * 4)]) = bv;
  } else {
    if (t >= 2 && t <= 17) {             // interior: gx in [x0, x0+256)
      const int xg = x0 - HALOC + 16 * t + n;
      if (!finalKer) {
        *(f32x4*)(ob + (size_t)xg * NCH + g * 4) = v;
      } else {
#pragma unroll
        for (int r = 0; r < 4; ++r) ob[(size_t)(g * 4 + r) * LL + xg] = v[r];
      }
    }
  }
}

#define STAGE(az, ak, agh, UPDZ, MODE)                                          \
  do {                                                                          \
    const __bf16* RS_ = S[rb];                                                  \
    __bf16* WS_ = S[rb ^ 1];                                                    \
    tileStage<MODE, UPDZ>(wv +  0, kz0, kf0, az, ak, agh, RS_, WS_, af0, af1,   \
                          af2, lane, g, n, leftE, rightE, ob, x0, finalKer);    \
    tileStage<MODE, UPDZ>(wv +  4, kz1, kf1, az, ak, agh, RS_, WS_, af0, af1,   \
                          af2, lane, g, n, leftE, rightE, ob, x0, finalKer);    \
    tileStage<MODE, UPDZ>(wv +  8, kz2, kf2, az, ak, agh, RS_, WS_, af0, af1,   \
                          af2, lane, g, n, leftE, rightE, ob, x0, finalKer);    \
    tileStage<MODE, UPDZ>(wv + 12, kz3, kf3, az, ak, agh, RS_, WS_, af0, af1,   \
                          af2, lane, g, n, leftE, rightE, ob, x0, finalKer);    \
    tileStage<MODE, UPDZ>(wv + 16, kz4, kf4, az, ak, agh, RS_, WS_, af0, af1,   \
                          af2, lane, g, n, leftE, rightE, ob, x0, finalKer);    \
  } while (0)

__global__ __launch_bounds__(256, 4) void multistep_kernel(
    const float* __restrict__ zin,   // fp32 transposed [b][x][ch]
    float* __restrict__ zout,        // fp32 transposed (row-major if finalKer)
    const float* __restrict__ W,     // [o][i][k] 16x16x5
    const int* __restrict__ tptr, int finalKer)
{
  __shared__ __align__(16) __bf16 S[2][SLABC * NCH];

  const int b = blockIdx.y, bx = blockIdx.x;
  const int x0 = bx * TX;
  const bool leftE = (bx == 0), rightE = (bx == NBX - 1);
  const float h = (float)(*tptr) / (float)NSTEPS;
  const int tid = threadIdx.x, lane = tid & 63, wv = tid >> 6;
  const int g = lane >> 4, n = lane & 15;

  const float* __restrict__ zb = zin + (size_t)b * NCH * LL;
  float* __restrict__ ob = zout + (size_t)b * NCH * LL;

  const bf16x8 af0 = mkA(W, 0, g, n);
  const bf16x8 af1 = mkA(W, 1, g, n);
  const bf16x8 af2 = mkA(W, 2, g, n);

  // Load z slab -> S[0] (bf16, swizzled); coalesced (4 threads per 64B line).
  for (int q = tid; q < SLABC * 4; q += 256) {
    const int s = q >> 2, cg = (q & 3) * 4;
    int gx = x0 - HALOC + s;
    gx = min(max(gx, 0), LL - 1);
    const float4 v = *(const float4*)(zb + (size_t)gx * NCH + cg);
    bf16x4 bv = { (__bf16)v.x, (__bf16)v.y, (__bf16)v.z, (__bf16)v.w };
    *(bf16x4*)(&S[0][ldsIdx(s, cg)]) = bv;
  }

  // fp32 state in named registers: thread owns (x=16t+n, ch 4g..4g+3), t=wv+4ti.
  f32x4 kz0 = ldState(zb, x0, wv +  0, n, g);
  f32x4 kz1 = ldState(zb, x0, wv +  4, n, g);
  f32x4 kz2 = ldState(zb, x0, wv +  8, n, g);
  f32x4 kz3 = ldState(zb, x0, wv + 12, n, g);
  f32x4 kz4 = ldState(zb, x0, wv + 16, n, g);
  f32x4 kf0 = {0.f,0.f,0.f,0.f}, kf1 = kf0, kf2 = kf0, kf3 = kf0, kf4 = kf0;
  __syncthreads();

  const float c13 = 1.0f / 3.0f, c23 = 2.0f / 3.0f;
  int rb = 0;
#pragma unroll 1
  for (int sp = 0; sp < SPK; ++sp) {
    STAGE(1.0f, 0.0f, h, false, 0);
    __syncthreads(); rb ^= 1;
    STAGE(0.75f, 0.25f, 0.25f * h, false, 0);
    __syncthreads(); rb ^= 1;
    if (sp != SPK - 1) {
      STAGE(c13, c23, c23 * h, true, 0);
      __syncthreads(); rb ^= 1;
    } else {
      STAGE(c13, c23, c23 * h, true, 1);
    }
  }
}

extern "C" void kernel_launch(void* const* d_in, const int* in_sizes, int n_in,
                              void* d_out, int out_size, void* d_ws, size_t ws_size,
                              hipStream_t stream) {
  const float* z0 = (const float*)d_in[0];
  const float* W  = (const float*)d_in[1];
  const int*   t  = (const int*)d_in[2];

  float* Q = (float*)d_out;   // transposed intermediate; final row-major dest
  float* P = (float*)d_ws;    // 16 MiB scratch

  dim3 grid(NBX, NB), block(256);
  transpose_kernel<<<grid, block, 0, stream>>>(z0, Q);

  for (int k = 1; k <= NKER; ++k) {
    if (k & 1) multistep_kernel<<<grid, block, 0, stream>>>(Q, P, W, t, 0);
    else       multistep_kernel<<<grid, block, 0, stream>>>(P, Q, W, t, k == NKER);
  }
}